// Round 6
// baseline (550.468 us; speedup 1.0000x reference)
//
#include <hip/hip_runtime.h>

#define L_ 4096
#define D_ 1536
#define NH 12
#define HD 128

typedef __attribute__((ext_vector_type(8))) __bf16 bf16x8;
typedef __attribute__((ext_vector_type(8))) unsigned short ushort8v;
typedef __attribute__((ext_vector_type(4))) float floatx4;

#if __has_builtin(__builtin_amdgcn_exp2f)
#define EXP2F(x) __builtin_amdgcn_exp2f(x)
#else
#define EXP2F(x) exp2f(x)
#endif

__device__ __forceinline__ unsigned short f2bf(float f) {
  union { float f; unsigned int u; } v; v.f = f;
  unsigned int u = v.u;
  return (unsigned short)((u + 0x7fffu + ((u >> 16) & 1u)) >> 16);
}
__device__ __forceinline__ float bf2f(unsigned short h) {
  union { unsigned int u; float f; } v; v.u = ((unsigned int)h) << 16;
  return v.f;
}

// ---------------- fp32 -> bf16 conversion (8 elems/thread) ----------------
__global__ __launch_bounds__(256) void cvt_f32_bf16(const float* __restrict__ in,
                                                    unsigned short* __restrict__ out,
                                                    int n8) {
  int i = blockIdx.x * 256 + threadIdx.x;
  if (i >= n8) return;
  const float4* p = (const float4*)(in + (size_t)i * 8);
  float4 a = p[0], b = p[1];
  ushort8v o;
  o[0] = f2bf(a.x); o[1] = f2bf(a.y); o[2] = f2bf(a.z); o[3] = f2bf(a.w);
  o[4] = f2bf(b.x); o[5] = f2bf(b.y); o[6] = f2bf(b.z); o[7] = f2bf(b.w);
  *(ushort8v*)(out + (size_t)i * 8) = o;
}

// ---------------- GEMM core (m97 structure), shared by both GEMM kernels ----
template <int MODE>
__device__ __forceinline__ void gemm_core(const unsigned short* __restrict__ A,
                                          const unsigned short* __restrict__ Bw,
                                          const float* __restrict__ bias,
                                          void* __restrict__ Cout,
                                          int M, int Nn, int K,
                                          int m0, int n0,
                                          unsigned short* As, unsigned short* Bs) {
  int t = threadIdx.x;
  int lane = t & 63, wv = t >> 6;
  int wm = (wv & 1) * 64, wn = (wv >> 1) * 64;
  floatx4 zero = {0.f, 0.f, 0.f, 0.f};
  floatx4 acc[4][4];
#pragma unroll
  for (int i = 0; i < 4; ++i)
#pragma unroll
    for (int j = 0; j < 4; ++j) acc[i][j] = zero;
  int fm = lane & 15, fk = (lane >> 4) * 8;

  for (int kt = 0; kt < K; kt += 32) {
    __syncthreads();
#pragma unroll
    for (int it = 0; it < 2; ++it) {
      int c = it * 256 + t;
      int row = c >> 2, col = (c & 3) * 8;
      const unsigned short* ga = A + (size_t)(m0 + row) * K + kt + col;
      const unsigned short* gb = Bw + (size_t)(n0 + row) * K + kt + col;
      __builtin_amdgcn_global_load_lds(
          (const __attribute__((address_space(1))) void*)ga,
          (__attribute__((address_space(3))) void*)((char*)As + (it * 256 + wv * 64) * 16),
          16, 0, 0);
      __builtin_amdgcn_global_load_lds(
          (const __attribute__((address_space(1))) void*)gb,
          (__attribute__((address_space(3))) void*)((char*)Bs + (it * 256 + wv * 64) * 16),
          16, 0, 0);
    }
    __syncthreads();
    bf16x8 af[4], bfr[4];
#pragma unroll
    for (int i = 0; i < 4; ++i) {
      af[i]  = *(const bf16x8*)&As[(wm + 16 * i + fm) * 32 + fk];
      bfr[i] = *(const bf16x8*)&Bs[(wn + 16 * i + fm) * 32 + fk];
    }
#pragma unroll
    for (int i = 0; i < 4; ++i)
#pragma unroll
      for (int j = 0; j < 4; ++j)
        acc[i][j] = __builtin_amdgcn_mfma_f32_16x16x32_bf16(af[i], bfr[j], acc[i][j], 0, 0, 0);
  }

  int fr = (lane >> 4) * 4;
#pragma unroll
  for (int j = 0; j < 4; ++j) {
    int col = n0 + wn + 16 * j + fm;
    float bz = bias[col];
#pragma unroll
    for (int i = 0; i < 4; ++i) {
      int row0 = m0 + wm + 16 * i + fr;
      if (MODE == 2) {
        ushort4 pk = make_ushort4(f2bf(acc[i][j][0] + bz), f2bf(acc[i][j][1] + bz),
                                  f2bf(acc[i][j][2] + bz), f2bf(acc[i][j][3] + bz));
        size_t off = (size_t)(row0 >> 5) * Nn * 32 + (size_t)col * 32 + (row0 & 31);
        *(ushort4*)&((unsigned short*)Cout)[off] = pk;
      } else {
#pragma unroll
        for (int r = 0; r < 4; ++r) {
          float val = acc[i][j][r] + bz;
          if (MODE == 1) ((unsigned short*)Cout)[(size_t)(row0 + r) * Nn + col] = f2bf(val);
          else           ((float*)Cout)[(size_t)(row0 + r) * Nn + col] = val;
        }
      }
    }
  }
}

template <int MODE>
__global__ __launch_bounds__(256) void gemm_bt(const unsigned short* __restrict__ A,
                                               const unsigned short* __restrict__ Bw,
                                               const float* __restrict__ bias,
                                               void* __restrict__ Cout,
                                               int M, int Nn, int K) {
  __shared__ unsigned short As[128 * 32];
  __shared__ unsigned short Bs[128 * 32];
  gemm_core<MODE>(A, Bw, bias, Cout, M, Nn, K, blockIdx.y * 128, blockIdx.x * 128, As, Bs);
}

// Fused QKV: one dispatch, 1152 blocks.
__global__ __launch_bounds__(256) void gemm_qkv(const unsigned short* __restrict__ xb,
                                                const unsigned short* __restrict__ wq,
                                                const unsigned short* __restrict__ wk,
                                                const unsigned short* __restrict__ wv,
                                                const float* __restrict__ bq,
                                                const float* __restrict__ bk,
                                                const float* __restrict__ bv,
                                                unsigned short* __restrict__ outq,
                                                unsigned short* __restrict__ outk,
                                                unsigned short* __restrict__ outv) {
  __shared__ unsigned short As[128 * 32];
  __shared__ unsigned short Bs[128 * 32];
  int which = blockIdx.x / (D_ / 128);
  int n0 = (blockIdx.x % (D_ / 128)) * 128;
  int m0 = blockIdx.y * 128;
  if (which == 0)
    gemm_core<1>(xb, wq, bq, outq, L_, D_, D_, m0, n0, As, Bs);
  else if (which == 1)
    gemm_core<1>(xb, wk, bk, outk, L_, D_, D_, m0, n0, As, Bs);
  else
    gemm_core<2>(xb, wv, bv, outv, L_, D_, D_, m0, n0, As, Bs);
}

// ---------------- fused RMSNorm (over D) + 3-axis RoPE, in-place bf16 -------
__global__ __launch_bounds__(256) void rmsrope(unsigned short* __restrict__ qb,
                                               unsigned short* __restrict__ kb,
                                               const float* __restrict__ gq,
                                               const float* __restrict__ gk,
                                               const float* __restrict__ fcos,
                                               const float* __restrict__ fsin,
                                               const int* __restrict__ grid_sizes) {
  int row = blockIdx.x;
  unsigned short* buf = (blockIdx.y == 0) ? qb : kb;
  const float* g = (blockIdx.y == 0) ? gq : gk;
  float osc = (blockIdx.y == 0) ? 0.1275174475f : 1.0f;  // log2(e)/sqrt(128)
  int t = threadIdx.x;
  float xr[3], xi[3];
#pragma unroll
  for (int i = 0; i < 3; ++i) {
    int p = t + i * 256;
    unsigned int raw = *(const unsigned int*)&buf[(size_t)row * D_ + 2 * p];
    xr[i] = bf2f((unsigned short)(raw & 0xffffu));
    xi[i] = bf2f((unsigned short)(raw >> 16));
  }
  float ss = 0.f;
#pragma unroll
  for (int i = 0; i < 3; ++i) ss += xr[i] * xr[i] + xi[i] * xi[i];
  for (int off = 32; off > 0; off >>= 1) ss += __shfl_down(ss, off);
  __shared__ float red[4];
  if ((t & 63) == 0) red[t >> 6] = ss;
  __syncthreads();
  float rs = rsqrtf((red[0] + red[1] + red[2] + red[3]) * (1.0f / D_) + 1e-6f);

  int gf = grid_sizes[0], gh = grid_sizes[1], gw = grid_sizes[2];
  int sl = gf * gh * gw;
  int hw = gh * gw;
  int fi = row / hw, rem = row - fi * hw;
  int hi = rem / gw, wi = rem - hi * gw;
  bool dorope = row < sl;
#pragma unroll
  for (int i = 0; i < 3; ++i) {
    int p = t + i * 256;
    int j = p & 63;
    float a = xr[i] * rs * g[2 * p];
    float b = xi[i] * rs * g[2 * p + 1];
    if (dorope) {
      int pos = (j < 22) ? fi : ((j < 43) ? hi : wi);
      float cs = fcos[pos * 64 + j], sn = fsin[pos * 64 + j];
      float oa = a * cs - b * sn;
      float ob = a * sn + b * cs;
      a = oa; b = ob;
    }
    a *= osc; b *= osc;
    unsigned int packed = (unsigned int)f2bf(a) | ((unsigned int)f2bf(b) << 16);
    *(unsigned int*)&buf[(size_t)row * D_ + 2 * p] = packed;
  }
}

// ---------------- MFMA flash attention v6: in-block split-K x2 --------------
// Block: 512 threads = 8 waves. Waves 0-3 (group 0) handle keys [0,2048),
// waves 4-7 (group 1) keys [2048,4096), for the SAME 128 q rows (wave pair
// (p, p+4) shares q). Two independent 32 KB LDS staging pipelines. Since
// softmax uses raw exp2 (no running max), partials combine as O=O0+O1,
// l=l0+l1 via one 64 KB LDS round-trip at the end. Grid 384 blocks ->
// 3072 waves (~12-16 waves/CU). V LDS layout [kg][d]: conflict-free PV reads.
__global__ __launch_bounds__(512, 4) void attn6(const unsigned short* __restrict__ Qb,
                                                const unsigned short* __restrict__ Kb,
                                                const unsigned short* __restrict__ Vt,
                                                unsigned short* __restrict__ Ob,
                                                const int* __restrict__ seq_lens) {
  __shared__ char smem[66048];  // 64 KB staging/combine + 512 B lbuf
  int t = threadIdx.x, lane = t & 63, w = t >> 6;
  int g = w >> 2, p = w & 3, tg = t & 255;
  unsigned short* Ksg = (unsigned short*)(smem + g * 32768);          // [2][4096]
  unsigned short* Vsg = (unsigned short*)(smem + g * 32768 + 16384);  // [2][4096]
  float* lbuf = (float*)(smem + 65536);                               // [4][32]

  int id = blockIdx.x;
  int u = (id & 7) * 48 + (id >> 3);   // XCD swizzle
  int h = u >> 5, qt = u & 31;
  int q0 = qt * 128 + p * 32;
  int seqlen = seq_lens[0];
  int fl = lane & 15, fg = lane >> 4;

  // Q B-fragments (pre-scaled): B[n=q][k=d]
  bf16x8 qf[2][4];
#pragma unroll
  for (int nj = 0; nj < 2; ++nj)
#pragma unroll
    for (int kd = 0; kd < 4; ++kd)
      qf[nj][kd] = *(const bf16x8*)&Qb[((size_t)(q0 + nj * 16 + fl) * NH + h) * HD + kd * 32 + fg * 8];

  // staging source pointers (key perm baked into K; V dest layout [kg][d])
  const unsigned short* kp[2];
  const unsigned short* vp[2];
#pragma unroll
  for (int i = 0; i < 2; ++i) {
    int c = tg + i * 256;
    int dgroup = c >> 5, permrow = c & 31;
    int kd = dgroup >> 2, fgc = dgroup & 3, mi = permrow >> 4, flc = permrow & 15;
    int key = (((flc & 12) << 1) | (flc & 3)) + (mi << 2);
    kp[i] = Kb + ((size_t)(g * 2048 + key) * NH + h) * HD + kd * 32 + fgc * 8;
    int vd = c & 127, vkg = c >> 7;
    vp[i] = Vt + (size_t)(g * 64) * (D_ * 32) + ((size_t)(h * HD + vd)) * 32 + vkg * 8;
  }
  const int STEP = 32 * NH * HD;

  auto stage = [&](int b) {
#pragma unroll
    for (int i = 0; i < 2; ++i) {
      __builtin_amdgcn_global_load_lds(
          (const __attribute__((address_space(1))) void*)kp[i],
          (__attribute__((address_space(3))) void*)&Ksg[b * 4096 + (i * 256 + p * 64) * 8],
          16, 0, 0);
      __builtin_amdgcn_global_load_lds(
          (const __attribute__((address_space(1))) void*)vp[i],
          (__attribute__((address_space(3))) void*)&Vsg[b * 4096 + (i * 256 + p * 64) * 8],
          16, 0, 0);
      kp[i] += STEP; vp[i] += STEP;
    }
  };

  floatx4 o[2][8];
  floatx4 zero = {0.f, 0.f, 0.f, 0.f};
#pragma unroll
  for (int nj = 0; nj < 2; ++nj)
#pragma unroll
    for (int nt = 0; nt < 8; ++nt) o[nj][nt] = zero;
  float lr[2] = {0.f, 0.f};

  stage(0);
  for (int kt = 0; kt < 2048; kt += 32) {
    int cur = (kt >> 5) & 1;
    __syncthreads();
    if (kt + 32 < 2048) stage(cur ^ 1);

    // S^T = K.Q^T
    floatx4 s[2][2];
    s[0][0] = zero; s[0][1] = zero; s[1][0] = zero; s[1][1] = zero;
#pragma unroll
    for (int kd = 0; kd < 4; ++kd)
#pragma unroll
      for (int mi = 0; mi < 2; ++mi) {
        bf16x8 kf = *(const bf16x8*)&Ksg[cur * 4096 + (((kd << 2) | fg) * 32 + (mi << 4) + fl) * 8];
#pragma unroll
        for (int nj = 0; nj < 2; ++nj)
          s[mi][nj] = __builtin_amdgcn_mfma_f32_16x16x32_bf16(kf, qf[nj][kd], s[mi][nj], 0, 0, 0);
      }

    // softmax: raw exp2 (scale pre-folded into Q), deferred l reduction
    bf16x8 pb[2];
    bool full = (g * 2048 + kt + 32 <= seqlen);
#pragma unroll
    for (int nj = 0; nj < 2; ++nj) {
      float pv[8];
      if (full) {
#pragma unroll
        for (int mi = 0; mi < 2; ++mi)
#pragma unroll
          for (int r = 0; r < 4; ++r) pv[mi * 4 + r] = EXP2F(s[mi][nj][r]);
      } else {
#pragma unroll
        for (int mi = 0; mi < 2; ++mi)
#pragma unroll
          for (int r = 0; r < 4; ++r) {
            int key = g * 2048 + kt + fg * 8 + mi * 4 + r;
            pv[mi * 4 + r] = (key < seqlen) ? EXP2F(s[mi][nj][r]) : 0.f;
          }
      }
      lr[nj] += ((pv[0] + pv[1]) + (pv[2] + pv[3])) + ((pv[4] + pv[5]) + (pv[6] + pv[7]));
      union { unsigned int u[4]; bf16x8 v; } pk;
#pragma unroll
      for (int jj = 0; jj < 4; ++jj) {
        unsigned int a = __builtin_bit_cast(unsigned int, pv[2 * jj]) + 0x8000u;
        unsigned int b = __builtin_bit_cast(unsigned int, pv[2 * jj + 1]) + 0x8000u;
        pk.u[jj] = (a >> 16) | (b & 0xffff0000u);
      }
      pb[nj] = pk.v;
    }

    // PV: A = pb (registers), B = V d-rows from LDS ([kg][d] layout)
#pragma unroll
    for (int nt = 0; nt < 8; ++nt) {
      bf16x8 vf = *(const bf16x8*)&Vsg[cur * 4096 + ((fg << 7) + (nt << 4) + fl) * 8];
#pragma unroll
      for (int nj = 0; nj < 2; ++nj)
        o[nj][nt] = __builtin_amdgcn_mfma_f32_16x16x32_bf16(pb[nj], vf, o[nj][nt], 0, 0, 0);
    }
  }

  // full l reduction (deferred out of the loop)
#pragma unroll
  for (int nj = 0; nj < 2; ++nj) {
    lr[nj] += __shfl_xor(lr[nj], 16);
    lr[nj] += __shfl_xor(lr[nj], 32);
  }

  // combine group partials via LDS
  __syncthreads();
  float* cb = (float*)smem;  // 16384 floats
  if (g == 1) {
    float* dst = cb + p * 4096 + lane * 64;
#pragma unroll
    for (int nj = 0; nj < 2; ++nj)
#pragma unroll
      for (int nt = 0; nt < 8; ++nt) ((floatx4*)dst)[nj * 8 + nt] = o[nj][nt];
    if (fg == 0) {
#pragma unroll
      for (int nj = 0; nj < 2; ++nj) lbuf[p * 32 + nj * 16 + fl] = lr[nj];
    }
  }
  __syncthreads();
  if (g == 0) {
    float* src = cb + p * 4096 + lane * 64;
#pragma unroll
    for (int nj = 0; nj < 2; ++nj) {
#pragma unroll
      for (int nt = 0; nt < 8; ++nt) {
        floatx4 add = ((floatx4*)src)[nj * 8 + nt];
        o[nj][nt][0] += add[0]; o[nj][nt][1] += add[1];
        o[nj][nt][2] += add[2]; o[nj][nt][3] += add[3];
      }
      lr[nj] += lbuf[p * 32 + nj * 16 + fl];
    }

    // epilogue: O /= l ; row q = q0+nj*16+fg*4+r, col d = nt*16+fl
#pragma unroll
    for (int nj = 0; nj < 2; ++nj) {
      float inv = 1.0f / lr[nj];
      float i0 = __shfl(inv, fg * 4 + 0);
      float i1 = __shfl(inv, fg * 4 + 1);
      float i2 = __shfl(inv, fg * 4 + 2);
      float i3 = __shfl(inv, fg * 4 + 3);
      int rowb = q0 + nj * 16 + fg * 4;
#pragma unroll
      for (int nt = 0; nt < 8; ++nt) {
        int dcol = h * HD + nt * 16 + fl;
        Ob[(size_t)(rowb + 0) * D_ + dcol] = f2bf(o[nj][nt][0] * i0);
        Ob[(size_t)(rowb + 1) * D_ + dcol] = f2bf(o[nj][nt][1] * i1);
        Ob[(size_t)(rowb + 2) * D_ + dcol] = f2bf(o[nj][nt][2] * i2);
        Ob[(size_t)(rowb + 3) * D_ + dcol] = f2bf(o[nj][nt][3] * i3);
      }
    }
  }
}

// ---------------- launch ----------------
extern "C" void kernel_launch(void* const* d_in, const int* in_sizes, int n_in,
                              void* d_out, int out_size, void* d_ws, size_t ws_size,
                              hipStream_t stream) {
  (void)in_sizes; (void)n_in; (void)out_size;
  const float* x    = (const float*)d_in[0];
  const int* seqln  = (const int*)d_in[1];
  const int* gsz    = (const int*)d_in[2];
  const float* fcos = (const float*)d_in[3];
  const float* fsin = (const float*)d_in[4];
  const float* Wq = (const float*)d_in[5];
  const float* bq = (const float*)d_in[6];
  const float* Wk = (const float*)d_in[7];
  const float* bk = (const float*)d_in[8];
  const float* Wv = (const float*)d_in[9];
  const float* bv = (const float*)d_in[10];
  const float* Wo = (const float*)d_in[11];
  const float* bo = (const float*)d_in[12];
  const float* gq = (const float*)d_in[13];
  const float* gk = (const float*)d_in[14];

  char* ws = (char*)d_ws;
  size_t LD2 = (size_t)L_ * D_ * 2;      // 12.58 MB
  size_t WD2 = (size_t)D_ * D_ * 2;      // 4.72 MB
  unsigned short* xb  = (unsigned short*)(ws);            // x bf16; later attn out
  unsigned short* qb  = (unsigned short*)(ws + LD2);
  unsigned short* kb  = (unsigned short*)(ws + 2 * LD2);
  unsigned short* vtb = (unsigned short*)(ws + 3 * LD2);  // V, K-tiled transposed
  unsigned short* wb0 = (unsigned short*)(ws + 4 * LD2);
  unsigned short* ab  = xb;

  int nx8 = L_ * D_ / 8, nw8 = D_ * D_ / 8;
  dim3 gg(D_ / 128, L_ / 128);

  cvt_f32_bf16<<<(nx8 + 255) / 256, 256, 0, stream>>>(x, xb, nx8);

  if (ws_size >= 4 * LD2 + 3 * WD2) {
    unsigned short* wb1 = (unsigned short*)(ws + 4 * LD2 + WD2);
    unsigned short* wb2 = (unsigned short*)(ws + 4 * LD2 + 2 * WD2);
    cvt_f32_bf16<<<(nw8 + 255) / 256, 256, 0, stream>>>(Wq, wb0, nw8);
    cvt_f32_bf16<<<(nw8 + 255) / 256, 256, 0, stream>>>(Wk, wb1, nw8);
    cvt_f32_bf16<<<(nw8 + 255) / 256, 256, 0, stream>>>(Wv, wb2, nw8);
    gemm_qkv<<<dim3(3 * D_ / 128, L_ / 128), 256, 0, stream>>>(
        xb, wb0, wb1, wb2, bq, bk, bv, qb, kb, vtb);
  } else {
    cvt_f32_bf16<<<(nw8 + 255) / 256, 256, 0, stream>>>(Wq, wb0, nw8);
    gemm_bt<1><<<gg, 256, 0, stream>>>(xb, wb0, bq, qb, L_, D_, D_);
    cvt_f32_bf16<<<(nw8 + 255) / 256, 256, 0, stream>>>(Wk, wb0, nw8);
    gemm_bt<1><<<gg, 256, 0, stream>>>(xb, wb0, bk, kb, L_, D_, D_);
    cvt_f32_bf16<<<(nw8 + 255) / 256, 256, 0, stream>>>(Wv, wb0, nw8);
    gemm_bt<2><<<gg, 256, 0, stream>>>(xb, wb0, bv, vtb, L_, D_, D_);
  }

  rmsrope<<<dim3(L_, 2), 256, 0, stream>>>(qb, kb, gq, gk, fcos, fsin, gsz);

  attn6<<<dim3(384), 512, 0, stream>>>(qb, kb, vtb, ab, seqln);

  cvt_f32_bf16<<<(nw8 + 255) / 256, 256, 0, stream>>>(Wo, wb0, nw8);
  gemm_bt<0><<<gg, 256, 0, stream>>>(ab, wb0, bo, d_out, L_, D_, D_);
}

// Round 7
// 404.753 us; speedup vs baseline: 1.3600x; 1.3600x over previous
//
#include <hip/hip_runtime.h>

#define L_ 4096
#define D_ 1536
#define NH 12
#define HD 128

typedef __attribute__((ext_vector_type(8))) __bf16 bf16x8;
typedef __attribute__((ext_vector_type(8))) unsigned short ushort8v;
typedef __attribute__((ext_vector_type(4))) float floatx4;

#if __has_builtin(__builtin_amdgcn_exp2f)
#define EXP2F(x) __builtin_amdgcn_exp2f(x)
#else
#define EXP2F(x) exp2f(x)
#endif

__device__ __forceinline__ unsigned short f2bf(float f) {
  union { float f; unsigned int u; } v; v.f = f;
  unsigned int u = v.u;
  return (unsigned short)((u + 0x7fffu + ((u >> 16) & 1u)) >> 16);
}
__device__ __forceinline__ float bf2f(unsigned short h) {
  union { unsigned int u; float f; } v; v.u = ((unsigned int)h) << 16;
  return v.f;
}

// ---------------- fp32 -> bf16 conversion (8 elems/thread) ----------------
__global__ __launch_bounds__(256) void cvt_f32_bf16(const float* __restrict__ in,
                                                    unsigned short* __restrict__ out,
                                                    int n8) {
  int i = blockIdx.x * 256 + threadIdx.x;
  if (i >= n8) return;
  const float4* p = (const float4*)(in + (size_t)i * 8);
  float4 a = p[0], b = p[1];
  ushort8v o;
  o[0] = f2bf(a.x); o[1] = f2bf(a.y); o[2] = f2bf(a.z); o[3] = f2bf(a.w);
  o[4] = f2bf(b.x); o[5] = f2bf(b.y); o[6] = f2bf(b.z); o[7] = f2bf(b.w);
  *(ushort8v*)(out + (size_t)i * 8) = o;
}

// ---------------- GEMM core (m97 structure) ----------------
template <int MODE>
__device__ __forceinline__ void gemm_core(const unsigned short* __restrict__ A,
                                          const unsigned short* __restrict__ Bw,
                                          const float* __restrict__ bias,
                                          void* __restrict__ Cout,
                                          int M, int Nn, int K,
                                          int m0, int n0,
                                          unsigned short* As, unsigned short* Bs) {
  int t = threadIdx.x;
  int lane = t & 63, wv = t >> 6;
  int wm = (wv & 1) * 64, wn = (wv >> 1) * 64;
  floatx4 zero = {0.f, 0.f, 0.f, 0.f};
  floatx4 acc[4][4];
#pragma unroll
  for (int i = 0; i < 4; ++i)
#pragma unroll
    for (int j = 0; j < 4; ++j) acc[i][j] = zero;
  int fm = lane & 15, fk = (lane >> 4) * 8;

  for (int kt = 0; kt < K; kt += 32) {
    __syncthreads();
#pragma unroll
    for (int it = 0; it < 2; ++it) {
      int c = it * 256 + t;
      int row = c >> 2, col = (c & 3) * 8;
      const unsigned short* ga = A + (size_t)(m0 + row) * K + kt + col;
      const unsigned short* gb = Bw + (size_t)(n0 + row) * K + kt + col;
      __builtin_amdgcn_global_load_lds(
          (const __attribute__((address_space(1))) void*)ga,
          (__attribute__((address_space(3))) void*)((char*)As + (it * 256 + wv * 64) * 16),
          16, 0, 0);
      __builtin_amdgcn_global_load_lds(
          (const __attribute__((address_space(1))) void*)gb,
          (__attribute__((address_space(3))) void*)((char*)Bs + (it * 256 + wv * 64) * 16),
          16, 0, 0);
    }
    __syncthreads();
    bf16x8 af[4], bfr[4];
#pragma unroll
    for (int i = 0; i < 4; ++i) {
      af[i]  = *(const bf16x8*)&As[(wm + 16 * i + fm) * 32 + fk];
      bfr[i] = *(const bf16x8*)&Bs[(wn + 16 * i + fm) * 32 + fk];
    }
#pragma unroll
    for (int i = 0; i < 4; ++i)
#pragma unroll
      for (int j = 0; j < 4; ++j)
        acc[i][j] = __builtin_amdgcn_mfma_f32_16x16x32_bf16(af[i], bfr[j], acc[i][j], 0, 0, 0);
  }

  int fr = (lane >> 4) * 4;
#pragma unroll
  for (int j = 0; j < 4; ++j) {
    int col = n0 + wn + 16 * j + fm;
    float bz = bias[col];
#pragma unroll
    for (int i = 0; i < 4; ++i) {
      int row0 = m0 + wm + 16 * i + fr;
      if (MODE == 2) {
        ushort4 pk = make_ushort4(f2bf(acc[i][j][0] + bz), f2bf(acc[i][j][1] + bz),
                                  f2bf(acc[i][j][2] + bz), f2bf(acc[i][j][3] + bz));
        size_t off = (size_t)(row0 >> 5) * Nn * 32 + (size_t)col * 32 + (row0 & 31);
        *(ushort4*)&((unsigned short*)Cout)[off] = pk;
      } else {
#pragma unroll
        for (int r = 0; r < 4; ++r) {
          float val = acc[i][j][r] + bz;
          if (MODE == 1) ((unsigned short*)Cout)[(size_t)(row0 + r) * Nn + col] = f2bf(val);
          else           ((float*)Cout)[(size_t)(row0 + r) * Nn + col] = val;
        }
      }
    }
  }
}

template <int MODE>
__global__ __launch_bounds__(256) void gemm_bt(const unsigned short* __restrict__ A,
                                               const unsigned short* __restrict__ Bw,
                                               const float* __restrict__ bias,
                                               void* __restrict__ Cout,
                                               int M, int Nn, int K) {
  __shared__ unsigned short As[128 * 32];
  __shared__ unsigned short Bs[128 * 32];
  gemm_core<MODE>(A, Bw, bias, Cout, M, Nn, K, blockIdx.y * 128, blockIdx.x * 128, As, Bs);
}

// Fused QKV: one dispatch, 1152 blocks.
__global__ __launch_bounds__(256) void gemm_qkv(const unsigned short* __restrict__ xb,
                                                const unsigned short* __restrict__ wq,
                                                const unsigned short* __restrict__ wk,
                                                const unsigned short* __restrict__ wv,
                                                const float* __restrict__ bq,
                                                const float* __restrict__ bk,
                                                const float* __restrict__ bv,
                                                unsigned short* __restrict__ outq,
                                                unsigned short* __restrict__ outk,
                                                unsigned short* __restrict__ outv) {
  __shared__ unsigned short As[128 * 32];
  __shared__ unsigned short Bs[128 * 32];
  int which = blockIdx.x / (D_ / 128);
  int n0 = (blockIdx.x % (D_ / 128)) * 128;
  int m0 = blockIdx.y * 128;
  if (which == 0)
    gemm_core<1>(xb, wq, bq, outq, L_, D_, D_, m0, n0, As, Bs);
  else if (which == 1)
    gemm_core<1>(xb, wk, bk, outk, L_, D_, D_, m0, n0, As, Bs);
  else
    gemm_core<2>(xb, wv, bv, outv, L_, D_, D_, m0, n0, As, Bs);
}

// ---------------- fused RMSNorm (over D) + 3-axis RoPE, in-place bf16 -------
__global__ __launch_bounds__(256) void rmsrope(unsigned short* __restrict__ qb,
                                               unsigned short* __restrict__ kb,
                                               const float* __restrict__ gq,
                                               const float* __restrict__ gk,
                                               const float* __restrict__ fcos,
                                               const float* __restrict__ fsin,
                                               const int* __restrict__ grid_sizes) {
  int row = blockIdx.x;
  unsigned short* buf = (blockIdx.y == 0) ? qb : kb;
  const float* g = (blockIdx.y == 0) ? gq : gk;
  float osc = (blockIdx.y == 0) ? 0.1275174475f : 1.0f;  // log2(e)/sqrt(128)
  int t = threadIdx.x;
  float xr[3], xi[3];
#pragma unroll
  for (int i = 0; i < 3; ++i) {
    int p = t + i * 256;
    unsigned int raw = *(const unsigned int*)&buf[(size_t)row * D_ + 2 * p];
    xr[i] = bf2f((unsigned short)(raw & 0xffffu));
    xi[i] = bf2f((unsigned short)(raw >> 16));
  }
  float ss = 0.f;
#pragma unroll
  for (int i = 0; i < 3; ++i) ss += xr[i] * xr[i] + xi[i] * xi[i];
  for (int off = 32; off > 0; off >>= 1) ss += __shfl_down(ss, off);
  __shared__ float red[4];
  if ((t & 63) == 0) red[t >> 6] = ss;
  __syncthreads();
  float rs = rsqrtf((red[0] + red[1] + red[2] + red[3]) * (1.0f / D_) + 1e-6f);

  int gf = grid_sizes[0], gh = grid_sizes[1], gw = grid_sizes[2];
  int sl = gf * gh * gw;
  int hw = gh * gw;
  int fi = row / hw, rem = row - fi * hw;
  int hi = rem / gw, wi = rem - hi * gw;
  bool dorope = row < sl;
#pragma unroll
  for (int i = 0; i < 3; ++i) {
    int p = t + i * 256;
    int j = p & 63;
    float a = xr[i] * rs * g[2 * p];
    float b = xi[i] * rs * g[2 * p + 1];
    if (dorope) {
      int pos = (j < 22) ? fi : ((j < 43) ? hi : wi);
      float cs = fcos[pos * 64 + j], sn = fsin[pos * 64 + j];
      float oa = a * cs - b * sn;
      float ob = a * sn + b * cs;
      a = oa; b = ob;
    }
    a *= osc; b *= osc;
    unsigned int packed = (unsigned int)f2bf(a) | ((unsigned int)f2bf(b) << 16);
    *(unsigned int*)&buf[(size_t)row * D_ + 2 * p] = packed;
  }
}

// ---------------- MFMA flash attention v7: split-K ACROSS BLOCKS x2 --------
// Same per-wave structure as attn5 (proven VGPR~76, no spill), but each block
// handles only half the keys and writes fp32 partial O + partial l (raw exp2
// partials combine as sums). Grid 768 -> 3 blocks/CU = 12 waves/CU.
__global__ __launch_bounds__(256, 2) void attn7(const unsigned short* __restrict__ Qb,
                                                const unsigned short* __restrict__ Kb,
                                                const unsigned short* __restrict__ Vt,
                                                float* __restrict__ Op0,
                                                float* __restrict__ Op1,
                                                float* __restrict__ lp,
                                                const int* __restrict__ seq_lens) {
  __shared__ unsigned short Ks[2][4096];
  __shared__ unsigned short Vs[2][4096];
  int t = threadIdx.x, lane = t & 63, w = t >> 6;
  int id = blockIdx.x;
  int u2 = (id & 7) * 96 + (id >> 3);   // XCD swizzle over 768 blocks
  int half = u2 & 1, v = u2 >> 1;
  int h = v >> 5, qt = v & 31;
  int q0 = qt * 128 + w * 32;
  int kv0 = half * 2048;
  float* Opart = half ? Op1 : Op0;
  float* lpart = lp + (size_t)half * L_ * NH;
  int seqlen = seq_lens[0];
  int fl = lane & 15, fg = lane >> 4;

  // Q B-fragments (pre-scaled): B[n=q][k=d]
  bf16x8 qf[2][4];
#pragma unroll
  for (int nj = 0; nj < 2; ++nj)
#pragma unroll
    for (int kd = 0; kd < 4; ++kd)
      qf[nj][kd] = *(const bf16x8*)&Qb[((size_t)(q0 + nj * 16 + fl) * NH + h) * HD + kd * 32 + fg * 8];

  // staging source pointers: K with key permutation; V dest layout [kg][d]
  const unsigned short* kp[2];
  const unsigned short* vp[2];
#pragma unroll
  for (int i = 0; i < 2; ++i) {
    int c = t + i * 256;
    int dgroup = c >> 5, permrow = c & 31;
    int kd = dgroup >> 2, fgc = dgroup & 3, mi = permrow >> 4, flc = permrow & 15;
    int key = (((flc & 12) << 1) | (flc & 3)) + (mi << 2);
    kp[i] = Kb + ((size_t)(kv0 + key) * NH + h) * HD + kd * 32 + fgc * 8;
    int vd = c & 127, vkg = c >> 7;
    vp[i] = Vt + (size_t)(kv0 >> 5) * (D_ * 32) + ((size_t)(h * HD + vd)) * 32 + vkg * 8;
  }
  const int STEP = 32 * NH * HD;

  auto stage = [&](int b) {
#pragma unroll
    for (int i = 0; i < 2; ++i) {
      __builtin_amdgcn_global_load_lds(
          (const __attribute__((address_space(1))) void*)kp[i],
          (__attribute__((address_space(3))) void*)&Ks[b][(i * 256 + w * 64) * 8],
          16, 0, 0);
      __builtin_amdgcn_global_load_lds(
          (const __attribute__((address_space(1))) void*)vp[i],
          (__attribute__((address_space(3))) void*)&Vs[b][(i * 256 + w * 64) * 8],
          16, 0, 0);
      kp[i] += STEP; vp[i] += STEP;
    }
  };

  floatx4 o[2][8];
  floatx4 zero = {0.f, 0.f, 0.f, 0.f};
#pragma unroll
  for (int nj = 0; nj < 2; ++nj)
#pragma unroll
    for (int nt = 0; nt < 8; ++nt) o[nj][nt] = zero;
  float lr[2] = {0.f, 0.f};

  stage(0);
  for (int kt = 0; kt < 2048; kt += 32) {
    int cur = (kt >> 5) & 1;
    __syncthreads();
    if (kt + 32 < 2048) stage(cur ^ 1);

    // S^T = K.Q^T
    floatx4 s[2][2];
    s[0][0] = zero; s[0][1] = zero; s[1][0] = zero; s[1][1] = zero;
#pragma unroll
    for (int kd = 0; kd < 4; ++kd)
#pragma unroll
      for (int mi = 0; mi < 2; ++mi) {
        bf16x8 kf = *(const bf16x8*)&Ks[cur][(((kd << 2) | fg) * 32 + (mi << 4) + fl) * 8];
#pragma unroll
        for (int nj = 0; nj < 2; ++nj)
          s[mi][nj] = __builtin_amdgcn_mfma_f32_16x16x32_bf16(kf, qf[nj][kd], s[mi][nj], 0, 0, 0);
      }

    // softmax: raw exp2 (scale pre-folded into Q), deferred l reduction
    bf16x8 pb[2];
    bool full = (kv0 + kt + 32 <= seqlen);
#pragma unroll
    for (int nj = 0; nj < 2; ++nj) {
      float pv[8];
      if (full) {
#pragma unroll
        for (int mi = 0; mi < 2; ++mi)
#pragma unroll
          for (int r = 0; r < 4; ++r) pv[mi * 4 + r] = EXP2F(s[mi][nj][r]);
      } else {
#pragma unroll
        for (int mi = 0; mi < 2; ++mi)
#pragma unroll
          for (int r = 0; r < 4; ++r) {
            int key = kv0 + kt + fg * 8 + mi * 4 + r;
            pv[mi * 4 + r] = (key < seqlen) ? EXP2F(s[mi][nj][r]) : 0.f;
          }
      }
      lr[nj] += ((pv[0] + pv[1]) + (pv[2] + pv[3])) + ((pv[4] + pv[5]) + (pv[6] + pv[7]));
      union { unsigned int u[4]; bf16x8 v; } pk;
#pragma unroll
      for (int jj = 0; jj < 4; ++jj) {
        unsigned int a = __builtin_bit_cast(unsigned int, pv[2 * jj]) + 0x8000u;
        unsigned int b = __builtin_bit_cast(unsigned int, pv[2 * jj + 1]) + 0x8000u;
        pk.u[jj] = (a >> 16) | (b & 0xffff0000u);
      }
      pb[nj] = pk.v;
    }

    // PV: A = pb (registers), B = V d-rows from LDS ([kg][d] layout)
#pragma unroll
    for (int nt = 0; nt < 8; ++nt) {
      bf16x8 vf = *(const bf16x8*)&Vs[cur][((fg << 7) + (nt << 4) + fl) * 8];
#pragma unroll
      for (int nj = 0; nj < 2; ++nj)
        o[nj][nt] = __builtin_amdgcn_mfma_f32_16x16x32_bf16(pb[nj], vf, o[nj][nt], 0, 0, 0);
    }
  }

  // deferred l reduction; write fp32 partials (no normalization here)
#pragma unroll
  for (int nj = 0; nj < 2; ++nj) {
    lr[nj] += __shfl_xor(lr[nj], 16);
    lr[nj] += __shfl_xor(lr[nj], 32);
    int rowb = q0 + nj * 16 + fg * 4;
#pragma unroll
    for (int nt = 0; nt < 8; ++nt) {
      int dcol = h * HD + nt * 16 + fl;
      Opart[(size_t)(rowb + 0) * D_ + dcol] = o[nj][nt][0];
      Opart[(size_t)(rowb + 1) * D_ + dcol] = o[nj][nt][1];
      Opart[(size_t)(rowb + 2) * D_ + dcol] = o[nj][nt][2];
      Opart[(size_t)(rowb + 3) * D_ + dcol] = o[nj][nt][3];
    }
    if (fg == 0) lpart[(size_t)(q0 + nj * 16 + fl) * NH + h] = lr[nj];
  }
}

// combine: out = (O0+O1) / (l0+l1), bf16
__global__ __launch_bounds__(256) void attn_combine(const float* __restrict__ Op0,
                                                    const float* __restrict__ Op1,
                                                    const float* __restrict__ lp,
                                                    unsigned short* __restrict__ out) {
  int gid = blockIdx.x * 256 + threadIdx.x;   // over L_*D_/8
  int q = gid / (D_ / 8);
  int col = (gid - q * (D_ / 8)) * 8;
  int h = col >> 7;
  float l0 = lp[(size_t)q * NH + h];
  float l1 = lp[(size_t)L_ * NH + (size_t)q * NH + h];
  float inv = 1.0f / (l0 + l1);
  const float4* p0 = (const float4*)(Op0 + (size_t)q * D_ + col);
  const float4* p1 = (const float4*)(Op1 + (size_t)q * D_ + col);
  float4 a0 = p0[0], a1 = p0[1], b0 = p1[0], b1 = p1[1];
  ushort8v o;
  o[0] = f2bf((a0.x + b0.x) * inv); o[1] = f2bf((a0.y + b0.y) * inv);
  o[2] = f2bf((a0.z + b0.z) * inv); o[3] = f2bf((a0.w + b0.w) * inv);
  o[4] = f2bf((a1.x + b1.x) * inv); o[5] = f2bf((a1.y + b1.y) * inv);
  o[6] = f2bf((a1.z + b1.z) * inv); o[7] = f2bf((a1.w + b1.w) * inv);
  *(ushort8v*)(out + (size_t)q * D_ + col) = o;
}

// ---------------- fallback attention (R5 attn5, bf16 direct out) ------------
__global__ __launch_bounds__(256, 2) void attn5(const unsigned short* __restrict__ Qb,
                                                const unsigned short* __restrict__ Kb,
                                                const unsigned short* __restrict__ Vt,
                                                unsigned short* __restrict__ Ob,
                                                const int* __restrict__ seq_lens) {
  __shared__ unsigned short Ks[2][4096];
  __shared__ unsigned short Vs[2][4096];
  int t = threadIdx.x, lane = t & 63, w = t >> 6;
  int id = blockIdx.x;
  int u = (id & 7) * 48 + (id >> 3);
  int h = u >> 5, qt = u & 31;
  int q0 = qt * 128 + w * 32;
  int seqlen = seq_lens[0];
  int fl = lane & 15, fg = lane >> 4;

  bf16x8 qf[2][4];
#pragma unroll
  for (int nj = 0; nj < 2; ++nj)
#pragma unroll
    for (int kd = 0; kd < 4; ++kd)
      qf[nj][kd] = *(const bf16x8*)&Qb[((size_t)(q0 + nj * 16 + fl) * NH + h) * HD + kd * 32 + fg * 8];

  const unsigned short* kp[2];
  const unsigned short* vp[2];
#pragma unroll
  for (int i = 0; i < 2; ++i) {
    int c = t + i * 256;
    int dgroup = c >> 5, permrow = c & 31;
    int kd = dgroup >> 2, fgc = dgroup & 3, mi = permrow >> 4, flc = permrow & 15;
    int key = (((flc & 12) << 1) | (flc & 3)) + (mi << 2);
    kp[i] = Kb + ((size_t)key * NH + h) * HD + kd * 32 + fgc * 8;
    int vd = c & 127, vkg = c >> 7;
    vp[i] = Vt + ((size_t)(h * HD + vd)) * 32 + vkg * 8;
  }
  const int STEP = 32 * NH * HD;

  auto stage = [&](int b) {
#pragma unroll
    for (int i = 0; i < 2; ++i) {
      __builtin_amdgcn_global_load_lds(
          (const __attribute__((address_space(1))) void*)kp[i],
          (__attribute__((address_space(3))) void*)&Ks[b][(i * 256 + w * 64) * 8],
          16, 0, 0);
      __builtin_amdgcn_global_load_lds(
          (const __attribute__((address_space(1))) void*)vp[i],
          (__attribute__((address_space(3))) void*)&Vs[b][(i * 256 + w * 64) * 8],
          16, 0, 0);
      kp[i] += STEP; vp[i] += STEP;
    }
  };

  floatx4 o[2][8];
  floatx4 zero = {0.f, 0.f, 0.f, 0.f};
#pragma unroll
  for (int nj = 0; nj < 2; ++nj)
#pragma unroll
    for (int nt = 0; nt < 8; ++nt) o[nj][nt] = zero;
  float lr[2] = {0.f, 0.f};

  stage(0);
  for (int kt = 0; kt < L_; kt += 32) {
    int cur = (kt >> 5) & 1;
    __syncthreads();
    if (kt + 32 < L_) stage(cur ^ 1);

    floatx4 s[2][2];
    s[0][0] = zero; s[0][1] = zero; s[1][0] = zero; s[1][1] = zero;
#pragma unroll
    for (int kd = 0; kd < 4; ++kd)
#pragma unroll
      for (int mi = 0; mi < 2; ++mi) {
        bf16x8 kf = *(const bf16x8*)&Ks[cur][(((kd << 2) | fg) * 32 + (mi << 4) + fl) * 8];
#pragma unroll
        for (int nj = 0; nj < 2; ++nj)
          s[mi][nj] = __builtin_amdgcn_mfma_f32_16x16x32_bf16(kf, qf[nj][kd], s[mi][nj], 0, 0, 0);
      }

    bf16x8 pb[2];
    bool full = (kt + 32 <= seqlen);
#pragma unroll
    for (int nj = 0; nj < 2; ++nj) {
      float pv[8];
      if (full) {
#pragma unroll
        for (int mi = 0; mi < 2; ++mi)
#pragma unroll
          for (int r = 0; r < 4; ++r) pv[mi * 4 + r] = EXP2F(s[mi][nj][r]);
      } else {
#pragma unroll
        for (int mi = 0; mi < 2; ++mi)
#pragma unroll
          for (int r = 0; r < 4; ++r) {
            int key = kt + fg * 8 + mi * 4 + r;
            pv[mi * 4 + r] = (key < seqlen) ? EXP2F(s[mi][nj][r]) : 0.f;
          }
      }
      lr[nj] += ((pv[0] + pv[1]) + (pv[2] + pv[3])) + ((pv[4] + pv[5]) + (pv[6] + pv[7]));
      union { unsigned int u[4]; bf16x8 v; } pk;
#pragma unroll
      for (int jj = 0; jj < 4; ++jj) {
        unsigned int a = __builtin_bit_cast(unsigned int, pv[2 * jj]) + 0x8000u;
        unsigned int b = __builtin_bit_cast(unsigned int, pv[2 * jj + 1]) + 0x8000u;
        pk.u[jj] = (a >> 16) | (b & 0xffff0000u);
      }
      pb[nj] = pk.v;
    }

#pragma unroll
    for (int nt = 0; nt < 8; ++nt) {
      bf16x8 vf = *(const bf16x8*)&Vs[cur][((fg << 7) + (nt << 4) + fl) * 8];
#pragma unroll
      for (int nj = 0; nj < 2; ++nj)
        o[nj][nt] = __builtin_amdgcn_mfma_f32_16x16x32_bf16(pb[nj], vf, o[nj][nt], 0, 0, 0);
    }
  }

#pragma unroll
  for (int nj = 0; nj < 2; ++nj) {
    lr[nj] += __shfl_xor(lr[nj], 16);
    lr[nj] += __shfl_xor(lr[nj], 32);
    float inv = 1.0f / lr[nj];
    int rowb = q0 + nj * 16 + fg * 4;
#pragma unroll
    for (int nt = 0; nt < 8; ++nt) {
      int dcol = h * HD + nt * 16 + fl;
      Ob[(size_t)(rowb + 0) * D_ + dcol] = f2bf(o[nj][nt][0] * inv);
      Ob[(size_t)(rowb + 1) * D_ + dcol] = f2bf(o[nj][nt][1] * inv);
      Ob[(size_t)(rowb + 2) * D_ + dcol] = f2bf(o[nj][nt][2] * inv);
      Ob[(size_t)(rowb + 3) * D_ + dcol] = f2bf(o[nj][nt][3] * inv);
    }
  }
}

// ---------------- launch ----------------
extern "C" void kernel_launch(void* const* d_in, const int* in_sizes, int n_in,
                              void* d_out, int out_size, void* d_ws, size_t ws_size,
                              hipStream_t stream) {
  (void)in_sizes; (void)n_in; (void)out_size;
  const float* x    = (const float*)d_in[0];
  const int* seqln  = (const int*)d_in[1];
  const int* gsz    = (const int*)d_in[2];
  const float* fcos = (const float*)d_in[3];
  const float* fsin = (const float*)d_in[4];
  const float* Wq = (const float*)d_in[5];
  const float* bq = (const float*)d_in[6];
  const float* Wk = (const float*)d_in[7];
  const float* bk = (const float*)d_in[8];
  const float* Wv = (const float*)d_in[9];
  const float* bv = (const float*)d_in[10];
  const float* Wo = (const float*)d_in[11];
  const float* bo = (const float*)d_in[12];
  const float* gq = (const float*)d_in[13];
  const float* gk = (const float*)d_in[14];

  char* ws = (char*)d_ws;
  size_t LD2  = (size_t)L_ * D_ * 2;     // 12.58 MB
  size_t WD2  = (size_t)D_ * D_ * 2;     // 4.72 MB
  size_t LD4  = (size_t)L_ * D_ * 4;     // 25.2 MB
  size_t LNH4 = (size_t)L_ * NH * 4;     // 196 KB
  unsigned short* xb  = (unsigned short*)(ws);            // x bf16; later attn out
  unsigned short* qb  = (unsigned short*)(ws + LD2);
  unsigned short* kb  = (unsigned short*)(ws + 2 * LD2);
  unsigned short* vtb = (unsigned short*)(ws + 3 * LD2);  // V, K-tiled transposed
  unsigned short* wb0 = (unsigned short*)(ws + 4 * LD2);
  unsigned short* ab  = xb;

  int nx8 = L_ * D_ / 8, nw8 = D_ * D_ / 8;
  dim3 gg(D_ / 128, L_ / 128);

  cvt_f32_bf16<<<(nx8 + 255) / 256, 256, 0, stream>>>(x, xb, nx8);

  bool fusedw = ws_size >= 4 * LD2 + 3 * WD2;
  if (fusedw) {
    unsigned short* wb1 = (unsigned short*)(ws + 4 * LD2 + WD2);
    unsigned short* wb2 = (unsigned short*)(ws + 4 * LD2 + 2 * WD2);
    cvt_f32_bf16<<<(nw8 + 255) / 256, 256, 0, stream>>>(Wq, wb0, nw8);
    cvt_f32_bf16<<<(nw8 + 255) / 256, 256, 0, stream>>>(Wk, wb1, nw8);
    cvt_f32_bf16<<<(nw8 + 255) / 256, 256, 0, stream>>>(Wv, wb2, nw8);
    gemm_qkv<<<dim3(3 * D_ / 128, L_ / 128), 256, 0, stream>>>(
        xb, wb0, wb1, wb2, bq, bk, bv, qb, kb, vtb);
  } else {
    cvt_f32_bf16<<<(nw8 + 255) / 256, 256, 0, stream>>>(Wq, wb0, nw8);
    gemm_bt<1><<<gg, 256, 0, stream>>>(xb, wb0, bq, qb, L_, D_, D_);
    cvt_f32_bf16<<<(nw8 + 255) / 256, 256, 0, stream>>>(Wk, wb0, nw8);
    gemm_bt<1><<<gg, 256, 0, stream>>>(xb, wb0, bk, kb, L_, D_, D_);
    cvt_f32_bf16<<<(nw8 + 255) / 256, 256, 0, stream>>>(Wv, wb0, nw8);
    gemm_bt<2><<<gg, 256, 0, stream>>>(xb, wb0, bv, vtb, L_, D_, D_);
  }

  rmsrope<<<dim3(L_, 2), 256, 0, stream>>>(qb, kb, gq, gk, fcos, fsin, gsz);

  size_t splitBase = 4 * LD2 + 3 * WD2;
  bool splitk = fusedw && (ws_size >= splitBase + LD4 + 2 * LNH4);
  if (splitk) {
    float* Op0 = (float*)d_out;                    // scratch; overwritten by Wo GEMM
    float* Op1 = (float*)(ws + splitBase);
    float* lp  = (float*)(ws + splitBase + LD4);
    attn7<<<dim3(768), 256, 0, stream>>>(qb, kb, vtb, Op0, Op1, lp, seqln);
    attn_combine<<<dim3(L_ * D_ / 8 / 256), 256, 0, stream>>>(Op0, Op1, lp, ab);
  } else {
    attn5<<<dim3(384), 256, 0, stream>>>(qb, kb, vtb, ab, seqln);
  }

  cvt_f32_bf16<<<(nw8 + 255) / 256, 256, 0, stream>>>(Wo, wb0, nw8);
  gemm_bt<0><<<gg, 256, 0, stream>>>(ab, wb0, bo, d_out, L_, D_, D_);
}